// Round 1
// 225.175 us; speedup vs baseline: 1.0226x; 1.0226x over previous
//
#include <hip/hip_runtime.h>
#include <hip/hip_bf16.h>
#include <hip/hip_fp16.h>

// GNN: 3x (H @ W -> sym-norm aggregate -> BN(eval)+ReLU) -> H @ lin_w + lin_b
// N=50000 nodes, E=800000 edges, D=64.
//
// r14: replace VALU/LDS-bound dense transform (k_mm/k_mm0, ~871 MB LDS
// traffic/layer ~= 11-13 us each) with LDS-free MFMA matmul:
//   - k_wprep transposes the 3 64x64 W into Wt[n][k] fp16 hi/lo split
//     (W ~= Whi + Wlo -> two MFMA terms == fp32-precision W).
//   - k_mm_mfma: 4 waves/block, 64 rows/block; wave computes 16 rows x 64
//     cols via 4 tiles of mfma_f32_16x16x32_f16, K=64 = 2 k-steps.
//     A-frag = 16B contiguous-k global load (lane l: row l&15, kchunk l>>4).
//     Layer 0 reads fp32 x, applies dinv row-scale, splits A hi/lo too.
// Aggregation pipeline (binned build + k_agg) unchanged from r10 best.
//
// LESSONS: (r6/r9) VGPR caps below natural need -> scratch spill (37-63 MB
// phantom traffic); k_agg natural = 64 VGPR at (256,6). (r7/r10) gather is
// compulsory-miss/latency bound: FETCH ~= 52 MB/layer; capacity misses ~0.
// (r8) 2 loads in flight per trip; 4 spills. (r11) nontemporal hint on
// bucket defeats cross-layer L2/L3 retention. (r12/r13) slot-63 degree
// packing + fixed-segment build = small net loss; grid 1536 vs 2048 = noise.

#define BN_EPS 1e-5f
#define CAP 64          // max in-degree capacity (Poisson(16): P(>=64) ~ 1e-18)
#define CHUNK 4096      // edges per pass1 block
#define SEGCAP 5120     // per-bin segment capacity (mean 4096, sd ~64)
#define NBINS_MAX 256

typedef _Float16 f16x8 __attribute__((ext_vector_type(8)));
typedef float f32x4 __attribute__((ext_vector_type(4)));

// ---------------- pass 1: bin edges by target range ----------------
__global__ __launch_bounds__(256) void k_bin_pairs(const int* __restrict__ row,
                                                   const int* __restrict__ col,
                                                   int* __restrict__ gfill,
                                                   unsigned int* __restrict__ gpairs,
                                                   int e, int nbins) {
    __shared__ unsigned int pl[CHUNK];   // 16 KB packed (src | dst<<16)
    __shared__ int bcnt[NBINS_MAX];
    __shared__ int bbase[NBINS_MAX];
    int tid = threadIdx.x;
    int base = blockIdx.x * CHUNK;
    for (int b = tid; b < nbins; b += 256) bcnt[b] = 0;
    __syncthreads();
    int nloc = e - base; if (nloc > CHUNK) nloc = CHUNK;
    #pragma unroll
    for (int it = 0; it < CHUNK / 1024; ++it) {      // 4 iters of int4
        int le = (it * 256 + tid) * 4;               // local edge base
        if (le + 3 < nloc) {
            int i4 = (base >> 2) + it * 256 + tid;
            int4 r = ((const int4*)row)[i4];
            int4 c = ((const int4*)col)[i4];
            atomicAdd(&bcnt[c.x >> 8], 1); pl[le + 0] = (unsigned)r.x | ((unsigned)c.x << 16);
            atomicAdd(&bcnt[c.y >> 8], 1); pl[le + 1] = (unsigned)r.y | ((unsigned)c.y << 16);
            atomicAdd(&bcnt[c.z >> 8], 1); pl[le + 2] = (unsigned)r.z | ((unsigned)c.z << 16);
            atomicAdd(&bcnt[c.w >> 8], 1); pl[le + 3] = (unsigned)r.w | ((unsigned)c.w << 16);
        } else {
            for (int j = 0; j < 4; ++j) {
                if (le + j < nloc) {
                    int rr = row[base + le + j];
                    int cc = col[base + le + j];
                    atomicAdd(&bcnt[cc >> 8], 1);
                    pl[le + j] = (unsigned)rr | ((unsigned)cc << 16);
                }
            }
        }
    }
    __syncthreads();
    for (int b = tid; b < nbins; b += 256) {
        bbase[b] = atomicAdd(&gfill[b], bcnt[b]);    // reserve segment space
        bcnt[b] = 0;
    }
    __syncthreads();
    for (int i = tid; i < nloc; i += 256) {
        unsigned int p = pl[i];
        int bin = p >> 24;                           // dst>>8
        int off = atomicAdd(&bcnt[bin], 1);
        int pos = bbase[bin] + off;
        if (pos < SEGCAP) gpairs[(size_t)bin * SEGCAP + pos] = p;
    }
}

// ---------------- pass 2: build bucket slab per bin in LDS ----------------
__global__ __launch_bounds__(256) void k_bucket_build(const unsigned int* __restrict__ gpairs,
                                                      const int* __restrict__ gfill,
                                                      int* __restrict__ cnt,
                                                      unsigned short* __restrict__ bucket,
                                                      int n) {
    __shared__ unsigned short lb[256 * CAP];  // 32 KB
    __shared__ int lc[256];
    int tid = threadIdx.x;
    int bin = blockIdx.x;
    lc[tid] = 0;
    __syncthreads();
    int m = gfill[bin]; if (m > SEGCAP) m = SEGCAP;
    const unsigned int* seg = gpairs + (size_t)bin * SEGCAP;
    for (int i = tid; i < m; i += 256) {
        unsigned int p = seg[i];
        int src = p & 0xffff;
        int dl = (p >> 16) & 255;
        int pos = atomicAdd(&lc[dl], 1);
        if (pos < CAP) lb[dl * CAP + pos] = (unsigned short)src;
    }
    __syncthreads();
    int nodebase = bin << 8;
    const int4* lb4 = (const int4*)lb;        // 8 int4 per 128 B row
    int4* gb4 = (int4*)bucket;
    for (int i = tid; i < 256 * 8; i += 256) {
        int rrow = i >> 3;
        int gnode = nodebase + rrow;
        if (gnode < n) gb4[(size_t)gnode * 8 + (i & 7)] = lb4[i];
    }
    int gnode = nodebase + tid;
    if (gnode < n) cnt[gnode] = lc[tid];
}

// ---------------- weight prep: Wt[layer][hi/lo][n][k] fp16 ----------------
// W is [k][n] fp32 row-major; store transposed (n-major) so B-fragments are
// 16B contiguous-k loads. hi = rn(W), lo = rn(W - hi): two-term MFMA gives
// effectively fp32 weight precision.
__global__ __launch_bounds__(256) void k_wprep(const float* __restrict__ Ws,
                                               __half* __restrict__ wt) {
    int l = blockIdx.x;
    int tid = threadIdx.x;
    const float* W = Ws + l * 4096;
    __half* hi = wt + (size_t)l * 8192;
    __half* lo = hi + 4096;
    for (int i = tid; i < 4096; i += 256) {
        int k = i >> 6, nn = i & 63;
        float w = W[k * 64 + nn];
        __half h = __float2half_rn(w);
        hi[nn * 64 + k] = h;
        lo[nn * 64 + k] = __float2half_rn(w - __half2float(h));
    }
}

// ---------------- dense 64x64 transform via MFMA (no LDS) ----------------
// Block = 256 threads = 4 waves; block covers 64 rows (16/wave).
// lane l: r = l&15 (row within stripe / col within tile), kg = l>>4.
// A-frag: A[row][kg*8 .. +8) -> one 16B load (k0=0) + one at k0=32.
// B-frag: Wt[col][kg*8 .. +8) same pattern. C/D: D[4*kg+i][r] (m89 layout).
// L0: fp32 input, dinv row-scale at load, A split hi/lo (input is exact fp32
// in the reference path; hi/lo keeps us at the r10 error level).
template<bool L0>
__global__ __launch_bounds__(256) void k_mm_mfma(const void* __restrict__ Ain,
                                                 const __half* __restrict__ wt,
                                                 const int* __restrict__ cnt,
                                                 __half* __restrict__ out, int n) {
    int tid = threadIdx.x;
    int w = tid >> 6;
    int lane = tid & 63;
    int r = lane & 15;
    int kg = lane >> 4;
    int row = blockIdx.x * 64 + w * 16 + r;
    bool inb = row < n;

    f16x8 ahi0 = {}, ahi1 = {}, alo0 = {}, alo1 = {};
    if (L0) {
        const float* A = (const float*)Ain;
        if (inb) {
            float di = rsqrtf((float)(cnt[row] + 1));
            const float4* ap0 = (const float4*)(A + (size_t)row * 64 + kg * 8);
            const float4* ap1 = (const float4*)(A + (size_t)row * 64 + 32 + kg * 8);
            float4 v0 = ap0[0], v1 = ap0[1];
            float4 v2 = ap1[0], v3 = ap1[1];
            float f[16] = {v0.x, v0.y, v0.z, v0.w, v1.x, v1.y, v1.z, v1.w,
                           v2.x, v2.y, v2.z, v2.w, v3.x, v3.y, v3.z, v3.w};
            #pragma unroll
            for (int i = 0; i < 8; ++i) {
                float s0 = f[i] * di, s1 = f[8 + i] * di;
                _Float16 h0 = (_Float16)s0, h1 = (_Float16)s1;
                ahi0[i] = h0; ahi1[i] = h1;
                alo0[i] = (_Float16)(s0 - (float)h0);
                alo1[i] = (_Float16)(s1 - (float)h1);
            }
        }
    } else {
        const __half* A = (const __half*)Ain;
        if (inb) {
            union { uint4 u; f16x8 h; } u0, u1;
            u0.u = *(const uint4*)(A + (size_t)row * 64 + kg * 8);
            u1.u = *(const uint4*)(A + (size_t)row * 64 + 32 + kg * 8);
            ahi0 = u0.h; ahi1 = u1.h;
        }
    }

    const __half* whi = wt;
    const __half* wlo = wt + 4096;
    f32x4 acc[4];
    #pragma unroll
    for (int t = 0; t < 4; ++t) {
        int cb = t * 16 + r;
        union { uint4 u; f16x8 h; } bh0, bh1, bl0, bl1;
        bh0.u = *(const uint4*)(whi + cb * 64 + kg * 8);
        bh1.u = *(const uint4*)(whi + cb * 64 + 32 + kg * 8);
        bl0.u = *(const uint4*)(wlo + cb * 64 + kg * 8);
        bl1.u = *(const uint4*)(wlo + cb * 64 + 32 + kg * 8);
        f32x4 a = {0.f, 0.f, 0.f, 0.f};
        a = __builtin_amdgcn_mfma_f32_16x16x32_f16(ahi0, bh0.h, a, 0, 0, 0);
        a = __builtin_amdgcn_mfma_f32_16x16x32_f16(ahi1, bh1.h, a, 0, 0, 0);
        a = __builtin_amdgcn_mfma_f32_16x16x32_f16(ahi0, bl0.h, a, 0, 0, 0);
        a = __builtin_amdgcn_mfma_f32_16x16x32_f16(ahi1, bl1.h, a, 0, 0, 0);
        if (L0) {
            a = __builtin_amdgcn_mfma_f32_16x16x32_f16(alo0, bh0.h, a, 0, 0, 0);
            a = __builtin_amdgcn_mfma_f32_16x16x32_f16(alo1, bh1.h, a, 0, 0, 0);
        }
        acc[t] = a;
    }

    int orow_base = blockIdx.x * 64 + w * 16 + 4 * kg;
    #pragma unroll
    for (int t = 0; t < 4; ++t) {
        #pragma unroll
        for (int i = 0; i < 4; ++i) {
            int orow = orow_base + i;
            if (orow < n) out[(size_t)orow * 64 + t * 16 + r] = __float2half_rn(acc[t][i]);
        }
    }
}

// ---------------- gather-sum + BN + ReLU (+ final projection) ----------------
// Wave per node (grid-stride). lane = 8*g + q: edge-slot g in [0,8), feature-
// octet q in [0,8); one float4 load = 8 fp16 = 8 edges per wave-instr.
// 2 loads in flight per trip (16 edges); (256,6); grid 2048: the proven
// r8/r10 occupancy/spill sweet spot (VGPR 64, zero scratch).
template<int LAYER, bool FINAL>
__global__ __launch_bounds__(256, 6) void k_agg(const __half* __restrict__ t,
                                                const int* __restrict__ cnt,
                                                const unsigned short* __restrict__ bucket,
                                                const float* __restrict__ bias,
                                                const float* __restrict__ gamma,
                                                const float* __restrict__ beta,
                                                const float* __restrict__ mean,
                                                const float* __restrict__ var,
                                                __half* __restrict__ hout,
                                                const float* __restrict__ lw,
                                                const float* __restrict__ lb,
                                                float* __restrict__ outp, int n) {
    int lane = threadIdx.x & 63;
    int g = lane >> 3;            // edge-slot group 0..7
    int q = lane & 7;             // feature octet -> features [8q, 8q+8)
    int qo = q << 3;
    // folded BN: h = ReLU(di*y*S + O), O = (b - m)*s + be
    float S[8], O[8], LW[8];
    #pragma unroll
    for (int i = 0; i < 8; ++i) {
        int f = qo + i;
        float s = gamma[f] * rsqrtf(var[f] + BN_EPS);
        S[i] = s;
        O[i] = fmaf(bias[f] - mean[f], s, beta[f]);
        if (FINAL) LW[i] = lw[f];
    }
    int wave = (blockIdx.x * blockDim.x + threadIdx.x) >> 6;
    int nwaves = (gridDim.x * blockDim.x) >> 6;
    union HV { float4 f4; __half2 h2[4]; };
    for (int node = wave; node < n; node += nwaves) {
        int c = cnt[node];
        int myidx = (int)bucket[node * CAP + lane];           // 128 B coalesced
        HV vself;
        vself.f4 = *(const float4*)(t + ((size_t)node << 6) + qo);  // hoisted
        float acc[8] = {0.f, 0.f, 0.f, 0.f, 0.f, 0.f, 0.f, 0.f};
        int cm1 = c - 1;
        for (int sub = 0; sub < c; sub += 16) {               // 16 edges, 2 loads
            int j1 = sub + g;
            int j2 = sub + 8 + g;
            int i1 = __shfl(myidx, (j1 < cm1 ? j1 : cm1), 64);
            int i2 = __shfl(myidx, (j2 < cm1 ? j2 : cm1), 64);
            float m1 = (j1 < c) ? 1.f : 0.f;
            float m2 = (j2 < c) ? 1.f : 0.f;
            HV v1, v2;
            v1.f4 = *(const float4*)(t + ((size_t)i1 << 6) + qo);
            v2.f4 = *(const float4*)(t + ((size_t)i2 << 6) + qo);
            #pragma unroll
            for (int p = 0; p < 4; ++p) {
                float2 a = __half22float2(v1.h2[p]);
                float2 b = __half22float2(v2.h2[p]);
                acc[2 * p]     = fmaf(m1, a.x, acc[2 * p]);
                acc[2 * p + 1] = fmaf(m1, a.y, acc[2 * p + 1]);
                acc[2 * p]     = fmaf(m2, b.x, acc[2 * p]);
                acc[2 * p + 1] = fmaf(m2, b.y, acc[2 * p + 1]);
            }
        }
        {   // self loop contribution, group 0 only (mask-FMA)
            float ms = (g == 0) ? 1.f : 0.f;
            #pragma unroll
            for (int p = 0; p < 4; ++p) {
                float2 a = __half22float2(vself.h2[p]);
                acc[2 * p]     = fmaf(ms, a.x, acc[2 * p]);
                acc[2 * p + 1] = fmaf(ms, a.y, acc[2 * p + 1]);
            }
        }
        // reduce 8 edge-slot groups -> lanes 0-7 hold the 64-dim agg
        #pragma unroll
        for (int i = 0; i < 8; ++i) {
            acc[i] += __shfl_down(acc[i], 32, 64);
            acc[i] += __shfl_down(acc[i], 16, 64);
            acc[i] += __shfl_down(acc[i], 8, 64);
        }
        float di = rsqrtf((float)(c + 1));
        if (FINAL) {
            float p = 0.f;
            #pragma unroll
            for (int i = 0; i < 8; ++i) {
                float h = fmaxf(fmaf(acc[i] * di, S[i], O[i]), 0.f);
                p = fmaf(h, LW[i], p);
            }
            p += __shfl_down(p, 4, 64);
            p += __shfl_down(p, 2, 64);
            p += __shfl_down(p, 1, 64);
            if (lane == 0) outp[node] = p + lb[0];
        } else if (g == 0) {
            union { __half2 h2[4]; uint4 u; } o;
            #pragma unroll
            for (int i = 0; i < 4; ++i) {
                float h0 = fmaxf(fmaf(acc[2 * i] * di, S[2 * i], O[2 * i]), 0.f);
                float h1 = fmaxf(fmaf(acc[2 * i + 1] * di, S[2 * i + 1], O[2 * i + 1]), 0.f);
                o.h2[i] = __floats2half2_rn(h0 * di, h1 * di);   // pre-scaled
            }
            *(uint4*)(hout + ((size_t)node << 6) + qo) = o.u;    // 128 B/wave
        }
    }
}

extern "C" void kernel_launch(void* const* d_in, const int* in_sizes, int n_in,
                              void* d_out, int out_size, void* d_ws, size_t ws_size,
                              hipStream_t stream) {
    const float* x    = (const float*)d_in[0];
    const int*   ei   = (const int*)d_in[1];
    const float* Ws   = (const float*)d_in[2];
    const float* bs   = (const float*)d_in[3];
    const float* gam  = (const float*)d_in[4];
    const float* bet  = (const float*)d_in[5];
    const float* mean = (const float*)d_in[6];
    const float* var  = (const float*)d_in[7];
    const float* lw   = (const float*)d_in[8];
    const float* lb   = (const float*)d_in[9];
    float* out = (float*)d_out;

    const int n = in_sizes[0] / 64;
    const int e = in_sizes[1] / 2;
    const int* row = ei;        // sources
    const int* col = ei + e;    // targets
    const int nbins = (n + 255) >> 8;   // 196

    // ws (ints): cnt[n] | gfill[256] | bucket[32n] | t16[32n] | h16[32n] | wt
    // gpairs (~4 MB) aliases t16 (dead until first k_mm_mfma<true>).
    int* ws_i = (int*)d_ws;
    int* cnt = ws_i;
    int* gfill = ws_i + n;
    unsigned short* bucket = (unsigned short*)(ws_i + n + 256);
    __half* t16 = (__half*)(ws_i + n + 256 + 32 * (size_t)n);
    __half* h16 = t16 + 64 * (size_t)n;
    __half* wt = (__half*)(((uintptr_t)(h16 + 64 * (size_t)n) + 15) & ~(uintptr_t)15);
    unsigned int* gpairs = (unsigned int*)t16;

    int nb_p1 = (e + CHUNK - 1) / CHUNK;   // 196
    int nb_mm = (n + 63) / 64;
    int nb_ag = 2048;                      // grid-stride

    hipMemsetAsync(gfill, 0, 256 * sizeof(int), stream);
    k_wprep<<<3, 256, 0, stream>>>(Ws, wt);
    k_bin_pairs<<<nb_p1, 256, 0, stream>>>(row, col, gfill, gpairs, e, nbins);
    k_bucket_build<<<nbins, 256, 0, stream>>>(gpairs, gfill, cnt, bucket, n);

    k_mm_mfma<true><<<nb_mm, 256, 0, stream>>>(x, wt, cnt, t16, n);
    k_agg<0, false><<<nb_ag, 256, 0, stream>>>(t16, cnt, bucket,
                                               bs, gam, bet, mean, var,
                                               h16, nullptr, nullptr, nullptr, n);
    k_mm_mfma<false><<<nb_mm, 256, 0, stream>>>(h16, wt + 8192, cnt, t16, n);
    k_agg<1, false><<<nb_ag, 256, 0, stream>>>(t16, cnt, bucket,
                                               bs + 64, gam + 64, bet + 64, mean + 64, var + 64,
                                               h16, nullptr, nullptr, nullptr, n);
    k_mm_mfma<false><<<nb_mm, 256, 0, stream>>>(h16, wt + 16384, cnt, t16, n);
    k_agg<2, true><<<nb_ag, 256, 0, stream>>>(t16, cnt, bucket,
                                              bs + 128, gam + 128, bet + 128, mean + 128, var + 128,
                                              nullptr, lw, lb, out, n);
}

// Round 2
// 218.787 us; speedup vs baseline: 1.0524x; 1.0292x over previous
//
#include <hip/hip_runtime.h>
#include <hip/hip_bf16.h>
#include <hip/hip_fp16.h>

// GNN: 3x (H @ W -> sym-norm aggregate -> BN(eval)+ReLU) -> H @ lin_w + lin_b
// N=50000 nodes, E=800000 edges, D=64.
//
// r15: pipeline k_agg. (r14: MFMA mm = +5us only -> mm lever spent; agg
// dominates at ~35-40us/layer, latency-chain bound.) Changes vs r14, k_agg
// only: (a) next-node cnt+bucket prefetch (hides bucket->shuffle chain under
// current node's gather); (b) 4 gather loads in flight (2 trips deep, refill
// in-loop); (c) launch_bounds (256,5) so the deeper pipeline fits without
// spill (natural ~80-90 VGPR; r6/r9: never cap below natural); grid 1280 =
// exact 5-block/CU residency. FMA order unchanged -> absmax bit-identical.
//
// LESSONS: (r6/r9) VGPR caps below natural need -> scratch spill (37-63 MB
// phantom traffic). (r7/r10) gather is compulsory-miss/latency bound: FETCH
// ~= 52 MB/layer; capacity misses ~0. (r11) nontemporal hint on bucket
// defeats cross-layer L2/L3 retention. (r12/r13) slot-63 degree packing +
// fixed-segment build = small net loss; grid 1536 vs 2048 = noise.
// (r14) MFMA transform (LDS-free, hi/lo fp16 split) replaces VALU mm: +5us.

#define BN_EPS 1e-5f
#define CAP 64          // max in-degree capacity (Poisson(16): P(>=64) ~ 1e-18)
#define CHUNK 4096      // edges per pass1 block
#define SEGCAP 5120     // per-bin segment capacity (mean 4096, sd ~64)
#define NBINS_MAX 256

typedef _Float16 f16x8 __attribute__((ext_vector_type(8)));
typedef float f32x4 __attribute__((ext_vector_type(4)));

// ---------------- pass 1: bin edges by target range ----------------
__global__ __launch_bounds__(256) void k_bin_pairs(const int* __restrict__ row,
                                                   const int* __restrict__ col,
                                                   int* __restrict__ gfill,
                                                   unsigned int* __restrict__ gpairs,
                                                   int e, int nbins) {
    __shared__ unsigned int pl[CHUNK];   // 16 KB packed (src | dst<<16)
    __shared__ int bcnt[NBINS_MAX];
    __shared__ int bbase[NBINS_MAX];
    int tid = threadIdx.x;
    int base = blockIdx.x * CHUNK;
    for (int b = tid; b < nbins; b += 256) bcnt[b] = 0;
    __syncthreads();
    int nloc = e - base; if (nloc > CHUNK) nloc = CHUNK;
    #pragma unroll
    for (int it = 0; it < CHUNK / 1024; ++it) {      // 4 iters of int4
        int le = (it * 256 + tid) * 4;               // local edge base
        if (le + 3 < nloc) {
            int i4 = (base >> 2) + it * 256 + tid;
            int4 r = ((const int4*)row)[i4];
            int4 c = ((const int4*)col)[i4];
            atomicAdd(&bcnt[c.x >> 8], 1); pl[le + 0] = (unsigned)r.x | ((unsigned)c.x << 16);
            atomicAdd(&bcnt[c.y >> 8], 1); pl[le + 1] = (unsigned)r.y | ((unsigned)c.y << 16);
            atomicAdd(&bcnt[c.z >> 8], 1); pl[le + 2] = (unsigned)r.z | ((unsigned)c.z << 16);
            atomicAdd(&bcnt[c.w >> 8], 1); pl[le + 3] = (unsigned)r.w | ((unsigned)c.w << 16);
        } else {
            for (int j = 0; j < 4; ++j) {
                if (le + j < nloc) {
                    int rr = row[base + le + j];
                    int cc = col[base + le + j];
                    atomicAdd(&bcnt[cc >> 8], 1);
                    pl[le + j] = (unsigned)rr | ((unsigned)cc << 16);
                }
            }
        }
    }
    __syncthreads();
    for (int b = tid; b < nbins; b += 256) {
        bbase[b] = atomicAdd(&gfill[b], bcnt[b]);    // reserve segment space
        bcnt[b] = 0;
    }
    __syncthreads();
    for (int i = tid; i < nloc; i += 256) {
        unsigned int p = pl[i];
        int bin = p >> 24;                           // dst>>8
        int off = atomicAdd(&bcnt[bin], 1);
        int pos = bbase[bin] + off;
        if (pos < SEGCAP) gpairs[(size_t)bin * SEGCAP + pos] = p;
    }
}

// ---------------- pass 2: build bucket slab per bin in LDS ----------------
__global__ __launch_bounds__(256) void k_bucket_build(const unsigned int* __restrict__ gpairs,
                                                      const int* __restrict__ gfill,
                                                      int* __restrict__ cnt,
                                                      unsigned short* __restrict__ bucket,
                                                      int n) {
    __shared__ unsigned short lb[256 * CAP];  // 32 KB
    __shared__ int lc[256];
    int tid = threadIdx.x;
    int bin = blockIdx.x;
    lc[tid] = 0;
    __syncthreads();
    int m = gfill[bin]; if (m > SEGCAP) m = SEGCAP;
    const unsigned int* seg = gpairs + (size_t)bin * SEGCAP;
    for (int i = tid; i < m; i += 256) {
        unsigned int p = seg[i];
        int src = p & 0xffff;
        int dl = (p >> 16) & 255;
        int pos = atomicAdd(&lc[dl], 1);
        if (pos < CAP) lb[dl * CAP + pos] = (unsigned short)src;
    }
    __syncthreads();
    int nodebase = bin << 8;
    const int4* lb4 = (const int4*)lb;        // 8 int4 per 128 B row
    int4* gb4 = (int4*)bucket;
    for (int i = tid; i < 256 * 8; i += 256) {
        int rrow = i >> 3;
        int gnode = nodebase + rrow;
        if (gnode < n) gb4[(size_t)gnode * 8 + (i & 7)] = lb4[i];
    }
    int gnode = nodebase + tid;
    if (gnode < n) cnt[gnode] = lc[tid];
}

// ---------------- weight prep: Wt[layer][hi/lo][n][k] fp16 ----------------
__global__ __launch_bounds__(256) void k_wprep(const float* __restrict__ Ws,
                                               __half* __restrict__ wt) {
    int l = blockIdx.x;
    int tid = threadIdx.x;
    const float* W = Ws + l * 4096;
    __half* hi = wt + (size_t)l * 8192;
    __half* lo = hi + 4096;
    for (int i = tid; i < 4096; i += 256) {
        int k = i >> 6, nn = i & 63;
        float w = W[k * 64 + nn];
        __half h = __float2half_rn(w);
        hi[nn * 64 + k] = h;
        lo[nn * 64 + k] = __float2half_rn(w - __half2float(h));
    }
}

// ---------------- dense 64x64 transform via MFMA (no LDS) ----------------
// Block = 256 threads = 4 waves; block covers 64 rows (16/wave).
// lane l: r = l&15, kg = l>>4. A-frag: A[row][kg*8..+8) 16B load + k0=32.
// B-frag: Wt[col][kg*8..+8). C/D: D[4*kg+i][r] (m89 layout).
template<bool L0>
__global__ __launch_bounds__(256) void k_mm_mfma(const void* __restrict__ Ain,
                                                 const __half* __restrict__ wt,
                                                 const int* __restrict__ cnt,
                                                 __half* __restrict__ out, int n) {
    int tid = threadIdx.x;
    int w = tid >> 6;
    int lane = tid & 63;
    int r = lane & 15;
    int kg = lane >> 4;
    int row = blockIdx.x * 64 + w * 16 + r;
    bool inb = row < n;

    f16x8 ahi0 = {}, ahi1 = {}, alo0 = {}, alo1 = {};
    if (L0) {
        const float* A = (const float*)Ain;
        if (inb) {
            float di = rsqrtf((float)(cnt[row] + 1));
            const float4* ap0 = (const float4*)(A + (size_t)row * 64 + kg * 8);
            const float4* ap1 = (const float4*)(A + (size_t)row * 64 + 32 + kg * 8);
            float4 v0 = ap0[0], v1 = ap0[1];
            float4 v2 = ap1[0], v3 = ap1[1];
            float f[16] = {v0.x, v0.y, v0.z, v0.w, v1.x, v1.y, v1.z, v1.w,
                           v2.x, v2.y, v2.z, v2.w, v3.x, v3.y, v3.z, v3.w};
            #pragma unroll
            for (int i = 0; i < 8; ++i) {
                float s0 = f[i] * di, s1 = f[8 + i] * di;
                _Float16 h0 = (_Float16)s0, h1 = (_Float16)s1;
                ahi0[i] = h0; ahi1[i] = h1;
                alo0[i] = (_Float16)(s0 - (float)h0);
                alo1[i] = (_Float16)(s1 - (float)h1);
            }
        }
    } else {
        const __half* A = (const __half*)Ain;
        if (inb) {
            union { uint4 u; f16x8 h; } u0, u1;
            u0.u = *(const uint4*)(A + (size_t)row * 64 + kg * 8);
            u1.u = *(const uint4*)(A + (size_t)row * 64 + 32 + kg * 8);
            ahi0 = u0.h; ahi1 = u1.h;
        }
    }

    const __half* whi = wt;
    const __half* wlo = wt + 4096;
    f32x4 acc[4];
    #pragma unroll
    for (int t = 0; t < 4; ++t) {
        int cb = t * 16 + r;
        union { uint4 u; f16x8 h; } bh0, bh1, bl0, bl1;
        bh0.u = *(const uint4*)(whi + cb * 64 + kg * 8);
        bh1.u = *(const uint4*)(whi + cb * 64 + 32 + kg * 8);
        bl0.u = *(const uint4*)(wlo + cb * 64 + kg * 8);
        bl1.u = *(const uint4*)(wlo + cb * 64 + 32 + kg * 8);
        f32x4 a = {0.f, 0.f, 0.f, 0.f};
        a = __builtin_amdgcn_mfma_f32_16x16x32_f16(ahi0, bh0.h, a, 0, 0, 0);
        a = __builtin_amdgcn_mfma_f32_16x16x32_f16(ahi1, bh1.h, a, 0, 0, 0);
        a = __builtin_amdgcn_mfma_f32_16x16x32_f16(ahi0, bl0.h, a, 0, 0, 0);
        a = __builtin_amdgcn_mfma_f32_16x16x32_f16(ahi1, bl1.h, a, 0, 0, 0);
        if (L0) {
            a = __builtin_amdgcn_mfma_f32_16x16x32_f16(alo0, bh0.h, a, 0, 0, 0);
            a = __builtin_amdgcn_mfma_f32_16x16x32_f16(alo1, bh1.h, a, 0, 0, 0);
        }
        acc[t] = a;
    }

    int orow_base = blockIdx.x * 64 + w * 16 + 4 * kg;
    #pragma unroll
    for (int t = 0; t < 4; ++t) {
        #pragma unroll
        for (int i = 0; i < 4; ++i) {
            int orow = orow_base + i;
            if (orow < n) out[(size_t)orow * 64 + t * 16 + r] = __float2half_rn(acc[t][i]);
        }
    }
}

// ---------------- gather-sum + BN + ReLU (+ final projection) ----------------
// Wave per node (grid-stride). lane = 8*g + q: edge-slot g in [0,8), feature-
// octet q in [0,8). r15 pipeline: next-node cnt+bucket prefetched one
// iteration ahead; 4 gather float4 loads in flight (edges 0-31), refilled
// in-loop for the rare c>32 tail. (256,5): 102-VGPR cap fits the deeper
// pipeline without spill; grid 1280 = exact residency.
template<int LAYER, bool FINAL>
__global__ __launch_bounds__(256, 5) void k_agg(const __half* __restrict__ t,
                                                const int* __restrict__ cnt,
                                                const unsigned short* __restrict__ bucket,
                                                const float* __restrict__ bias,
                                                const float* __restrict__ gamma,
                                                const float* __restrict__ beta,
                                                const float* __restrict__ mean,
                                                const float* __restrict__ var,
                                                __half* __restrict__ hout,
                                                const float* __restrict__ lw,
                                                const float* __restrict__ lb,
                                                float* __restrict__ outp, int n) {
    int lane = threadIdx.x & 63;
    int g = lane >> 3;            // edge-slot group 0..7
    int q = lane & 7;             // feature octet -> features [8q, 8q+8)
    int qo = q << 3;
    // folded BN: h = ReLU(di*y*S + O), O = (b - m)*s + be
    float S[8], O[8], LW[8];
    #pragma unroll
    for (int i = 0; i < 8; ++i) {
        int f = qo + i;
        float s = gamma[f] * rsqrtf(var[f] + BN_EPS);
        S[i] = s;
        O[i] = fmaf(bias[f] - mean[f], s, beta[f]);
        if (FINAL) LW[i] = lw[f];
    }
    int wave = (blockIdx.x * blockDim.x + threadIdx.x) >> 6;
    int nwaves = (gridDim.x * blockDim.x) >> 6;
    union HV { float4 f4; __half2 h2[4]; };
    int node = wave;
    int c_pf = 0, idx_pf = 0;
    if (node < n) {                                   // prologue prefetch
        c_pf = cnt[node];
        idx_pf = (int)bucket[(size_t)node * CAP + lane];
    }
    for (; node < n; node += nwaves) {
        int c = c_pf;
        int myidx = idx_pf;
        HV vself;
        vself.f4 = *(const float4*)(t + ((size_t)node << 6) + qo);
        int nn = node + nwaves;
        if (nn < n) {                                 // next-node prefetch
            c_pf = cnt[nn];
            idx_pf = (int)bucket[(size_t)nn * CAP + lane];
        }
        int cm1 = c - 1; if (cm1 < 0) cm1 = 0;
        // issue 4 gather loads (edges 0-31) up front
        int i1 = __shfl(myidx, (g < cm1 ? g : cm1), 64);
        int i2 = __shfl(myidx, (8 + g < cm1 ? 8 + g : cm1), 64);
        HV v1, v2, v3, v4;
        v1.f4 = *(const float4*)(t + ((size_t)i1 << 6) + qo);
        v2.f4 = *(const float4*)(t + ((size_t)i2 << 6) + qo);
        if (c > 16) {                                 // wave-uniform branch
            int i3 = __shfl(myidx, (16 + g < cm1 ? 16 + g : cm1), 64);
            int i4 = __shfl(myidx, (24 + g < cm1 ? 24 + g : cm1), 64);
            v3.f4 = *(const float4*)(t + ((size_t)i3 << 6) + qo);
            v4.f4 = *(const float4*)(t + ((size_t)i4 << 6) + qo);
        }
        float acc[8] = {0.f, 0.f, 0.f, 0.f, 0.f, 0.f, 0.f, 0.f};
        for (int sub = 0; sub < c; sub += 32) {       // 32 edges per iter
            float m1 = (sub + g < c) ? 1.f : 0.f;
            float m2 = (sub + 8 + g < c) ? 1.f : 0.f;
            #pragma unroll
            for (int p = 0; p < 4; ++p) {
                float2 a = __half22float2(v1.h2[p]);
                float2 b = __half22float2(v2.h2[p]);
                acc[2 * p]     = fmaf(m1, a.x, acc[2 * p]);
                acc[2 * p + 1] = fmaf(m1, a.y, acc[2 * p + 1]);
                acc[2 * p]     = fmaf(m2, b.x, acc[2 * p]);
                acc[2 * p + 1] = fmaf(m2, b.y, acc[2 * p + 1]);
            }
            if (sub + 32 < c) {                       // refill pair 1 (rare)
                int t1 = sub + 32 + g, t2 = sub + 40 + g;
                i1 = __shfl(myidx, (t1 < cm1 ? t1 : cm1), 64);
                i2 = __shfl(myidx, (t2 < cm1 ? t2 : cm1), 64);
                v1.f4 = *(const float4*)(t + ((size_t)i1 << 6) + qo);
                v2.f4 = *(const float4*)(t + ((size_t)i2 << 6) + qo);
            }
            if (sub + 16 < c) {
                float m3 = (sub + 16 + g < c) ? 1.f : 0.f;
                float m4 = (sub + 24 + g < c) ? 1.f : 0.f;
                #pragma unroll
                for (int p = 0; p < 4; ++p) {
                    float2 a = __half22float2(v3.h2[p]);
                    float2 b = __half22float2(v4.h2[p]);
                    acc[2 * p]     = fmaf(m3, a.x, acc[2 * p]);
                    acc[2 * p + 1] = fmaf(m3, a.y, acc[2 * p + 1]);
                    acc[2 * p]     = fmaf(m4, b.x, acc[2 * p]);
                    acc[2 * p + 1] = fmaf(m4, b.y, acc[2 * p + 1]);
                }
            }
            if (sub + 48 < c) {                       // refill pair 2 (rare)
                int t3 = sub + 48 + g, t4 = sub + 56 + g;
                int i3 = __shfl(myidx, (t3 < cm1 ? t3 : cm1), 64);
                int i4 = __shfl(myidx, (t4 < cm1 ? t4 : cm1), 64);
                v3.f4 = *(const float4*)(t + ((size_t)i3 << 6) + qo);
                v4.f4 = *(const float4*)(t + ((size_t)i4 << 6) + qo);
            }
        }
        {   // self loop contribution, group 0 only (mask-FMA)
            float ms = (g == 0) ? 1.f : 0.f;
            #pragma unroll
            for (int p = 0; p < 4; ++p) {
                float2 a = __half22float2(vself.h2[p]);
                acc[2 * p]     = fmaf(ms, a.x, acc[2 * p]);
                acc[2 * p + 1] = fmaf(ms, a.y, acc[2 * p + 1]);
            }
        }
        // reduce 8 edge-slot groups -> lanes 0-7 hold the 64-dim agg
        #pragma unroll
        for (int i = 0; i < 8; ++i) {
            acc[i] += __shfl_down(acc[i], 32, 64);
            acc[i] += __shfl_down(acc[i], 16, 64);
            acc[i] += __shfl_down(acc[i], 8, 64);
        }
        float di = rsqrtf((float)(c + 1));
        if (FINAL) {
            float p = 0.f;
            #pragma unroll
            for (int i = 0; i < 8; ++i) {
                float h = fmaxf(fmaf(acc[i] * di, S[i], O[i]), 0.f);
                p = fmaf(h, LW[i], p);
            }
            p += __shfl_down(p, 4, 64);
            p += __shfl_down(p, 2, 64);
            p += __shfl_down(p, 1, 64);
            if (lane == 0) outp[node] = p + lb[0];
        } else if (g == 0) {
            union { __half2 h2[4]; uint4 u; } o;
            #pragma unroll
            for (int i = 0; i < 4; ++i) {
                float h0 = fmaxf(fmaf(acc[2 * i] * di, S[2 * i], O[2 * i]), 0.f);
                float h1 = fmaxf(fmaf(acc[2 * i + 1] * di, S[2 * i + 1], O[2 * i + 1]), 0.f);
                o.h2[i] = __floats2half2_rn(h0 * di, h1 * di);   // pre-scaled
            }
            *(uint4*)(hout + ((size_t)node << 6) + qo) = o.u;    // 128 B/wave
        }
    }
}

extern "C" void kernel_launch(void* const* d_in, const int* in_sizes, int n_in,
                              void* d_out, int out_size, void* d_ws, size_t ws_size,
                              hipStream_t stream) {
    const float* x    = (const float*)d_in[0];
    const int*   ei   = (const int*)d_in[1];
    const float* Ws   = (const float*)d_in[2];
    const float* bs   = (const float*)d_in[3];
    const float* gam  = (const float*)d_in[4];
    const float* bet  = (const float*)d_in[5];
    const float* mean = (const float*)d_in[6];
    const float* var  = (const float*)d_in[7];
    const float* lw   = (const float*)d_in[8];
    const float* lb   = (const float*)d_in[9];
    float* out = (float*)d_out;

    const int n = in_sizes[0] / 64;
    const int e = in_sizes[1] / 2;
    const int* row = ei;        // sources
    const int* col = ei + e;    // targets
    const int nbins = (n + 255) >> 8;   // 196

    // ws (ints): cnt[n] | gfill[256] | bucket[32n] | t16[32n] | h16[32n] | wt
    // gpairs (~4 MB) aliases t16 (dead until first k_mm_mfma<true>).
    int* ws_i = (int*)d_ws;
    int* cnt = ws_i;
    int* gfill = ws_i + n;
    unsigned short* bucket = (unsigned short*)(ws_i + n + 256);
    __half* t16 = (__half*)(ws_i + n + 256 + 32 * (size_t)n);
    __half* h16 = t16 + 64 * (size_t)n;
    __half* wt = (__half*)(((uintptr_t)(h16 + 64 * (size_t)n) + 15) & ~(uintptr_t)15);
    unsigned int* gpairs = (unsigned int*)t16;

    int nb_p1 = (e + CHUNK - 1) / CHUNK;   // 196
    int nb_mm = (n + 63) / 64;
    int nb_ag = 1280;                      // 5 blocks/CU x 256 CU residency

    hipMemsetAsync(gfill, 0, 256 * sizeof(int), stream);
    k_wprep<<<3, 256, 0, stream>>>(Ws, wt);
    k_bin_pairs<<<nb_p1, 256, 0, stream>>>(row, col, gfill, gpairs, e, nbins);
    k_bucket_build<<<nbins, 256, 0, stream>>>(gpairs, gfill, cnt, bucket, n);

    k_mm_mfma<true><<<nb_mm, 256, 0, stream>>>(x, wt, cnt, t16, n);
    k_agg<0, false><<<nb_ag, 256, 0, stream>>>(t16, cnt, bucket,
                                               bs, gam, bet, mean, var,
                                               h16, nullptr, nullptr, nullptr, n);
    k_mm_mfma<false><<<nb_mm, 256, 0, stream>>>(h16, wt + 8192, cnt, t16, n);
    k_agg<1, false><<<nb_ag, 256, 0, stream>>>(t16, cnt, bucket,
                                               bs + 64, gam + 64, bet + 64, mean + 64, var + 64,
                                               h16, nullptr, nullptr, nullptr, n);
    k_mm_mfma<false><<<nb_mm, 256, 0, stream>>>(h16, wt + 16384, cnt, t16, n);
    k_agg<2, true><<<nb_ag, 256, 0, stream>>>(t16, cnt, bucket,
                                              bs + 128, gam + 128, bet + 128, mean + 128, var + 128,
                                              nullptr, lw, lb, out, n);
}